// Round 13
// baseline (47439.273 us; speedup 1.0000x reference)
//
#include <hip/hip_runtime.h>
#include <stdint.h>
#include <math.h>

#define HD 1024
#define BB 8
#define LL 2048
#define NBLK 256
#define NTHR 512

typedef unsigned short u16;
typedef unsigned int u32;
typedef unsigned long long u64;

using bf16x8 = __attribute__((ext_vector_type(8))) short;
using f32x4  = __attribute__((ext_vector_type(4))) float;

__device__ __forceinline__ u16 f2bf(float f) {
  u32 x = __float_as_uint(f);
  x += 0x7fffu + ((x >> 16) & 1u);
  return (u16)(x >> 16);
}
__device__ __forceinline__ float bf2f(u16 u) {
  return __uint_as_float(((u32)u) << 16);
}
__device__ __forceinline__ float dot4(float4 a, float4 b) {
  return fmaf(a.x, b.x, fmaf(a.y, b.y, fmaf(a.z, b.z, a.w * b.w)));
}
__device__ __forceinline__ float sigmoidf(float x) { return 1.f / (1.f + expf(-x)); }
__device__ __forceinline__ float4 unpk4g(u64 v) {
  u32 lo = (u32)v, hi = (u32)(v >> 32);
  float4 f;
  f.x = __uint_as_float(lo << 16);
  f.y = __uint_as_float(lo & 0xffff0000u);
  f.z = __uint_as_float(hi << 16);
  f.w = __uint_as_float(hi & 0xffff0000u);
  return f;
}

// ---- coherent LLC accesses via relaxed agent atomics (compiler-tracked) ----
__device__ __forceinline__ float2 cload2f(const u64* p) {
  u64 v = __hip_atomic_load(p, __ATOMIC_RELAXED, __HIP_MEMORY_SCOPE_AGENT);
  float2 r;
  r.x = __uint_as_float((u32)v);
  r.y = __uint_as_float((u32)(v >> 32));
  return r;
}
__device__ __forceinline__ void cstore1(float* p, float a) {
  __hip_atomic_store((u32*)p, __float_as_uint(a), __ATOMIC_RELAXED, __HIP_MEMORY_SCOPE_AGENT);
}

// ---- global barrier: 8 lines x 32 arrivals, monotonic, 4 instances ----
// arrive: 1 RMW on line bid&7. wait: t0 issues 8 independent scalar loads
// (pipelined, ~1 round trip), sums, compares 256*(k+1).
__device__ __forceinline__ void bar_arrive(u32* bar, int n, int bid) {
  int inst = n & 3;
  __hip_atomic_fetch_add(&bar[(inst * 8 + (bid & 7)) * 16], 1u,
                         __ATOMIC_RELAXED, __HIP_MEMORY_SCOPE_AGENT);
}
__device__ __forceinline__ void bar_wait(u32* bar, int n) {
  int inst = n & 3;
  u32 tgt = (u32)((n >> 2) + 1) * 256u;
  for (;;) {
    u32 s = 0;
#pragma unroll
    for (int i = 0; i < 8; i++)
      s += __hip_atomic_load(&bar[(inst * 8 + i) * 16],
                             __ATOMIC_RELAXED, __HIP_MEMORY_SCOPE_AGENT);
    if (s >= tgt) break;
    __builtin_amdgcn_s_sleep(1);
  }
}

// ---------------- input LN: x [16384,1024] f32 -> xn bf16 ----------------
__global__ __launch_bounds__(256) void k_ln_x(const float* __restrict__ x,
    const float* __restrict__ g, const float* __restrict__ b,
    u16* __restrict__ xn) {
  int row = blockIdx.x;
  int t = threadIdx.x;
  const float4* xr = (const float4*)(x + (size_t)row * HD);
  float4 v = xr[t];
  float s = v.x + v.y + v.z + v.w;
  float ss = v.x * v.x + v.y * v.y + v.z * v.z + v.w * v.w;
#pragma unroll
  for (int off = 32; off; off >>= 1) { s += __shfl_down(s, off); ss += __shfl_down(ss, off); }
  __shared__ float red[8];
  if ((t & 63) == 0) { red[t >> 6] = s; red[4 + (t >> 6)] = ss; }
  __syncthreads();
  s = red[0] + red[1] + red[2] + red[3];
  ss = red[4] + red[5] + red[6] + red[7];
  float m = s * (1.0f / HD);
  float rstd = rsqrtf(ss * (1.0f / HD) - m * m + 1e-5f);
  float4 gv = ((const float4*)g)[t];
  float4 bv = ((const float4*)b)[t];
  ushort4 o;
  o.x = f2bf((v.x - m) * rstd * gv.x + bv.x);
  o.y = f2bf((v.y - m) * rstd * gv.y + bv.y);
  o.z = f2bf((v.z - m) * rstd * gv.z + bv.z);
  o.w = f2bf((v.w - m) * rstd * gv.w + bv.w);
  *(ushort4*)(xn + (size_t)row * HD + t * 4) = o;
}

// ---------------- output LN, in place on f32 rows ----------------
__global__ __launch_bounds__(256) void k_out_ln(float* __restrict__ y,
    const float* __restrict__ g, const float* __restrict__ b) {
  int row = blockIdx.x;
  int t = threadIdx.x;
  float4* yr = (float4*)(y + (size_t)row * HD);
  float4 v = yr[t];
  float s = v.x + v.y + v.z + v.w;
  float ss = v.x * v.x + v.y * v.y + v.z * v.z + v.w * v.w;
#pragma unroll
  for (int off = 32; off; off >>= 1) { s += __shfl_down(s, off); ss += __shfl_down(ss, off); }
  __shared__ float red[8];
  if ((t & 63) == 0) { red[t >> 6] = s; red[4 + (t >> 6)] = ss; }
  __syncthreads();
  s = red[0] + red[1] + red[2] + red[3];
  ss = red[4] + red[5] + red[6] + red[7];
  float m = s * (1.0f / HD);
  float rstd = rsqrtf(ss * (1.0f / HD) - m * m + 1e-5f);
  float4 gv = ((const float4*)g)[t];
  float4 bv = ((const float4*)b)[t];
  float4 o;
  o.x = (v.x - m) * rstd * gv.x + bv.x;
  o.y = (v.y - m) * rstd * gv.y + bv.y;
  o.z = (v.z - m) * rstd * gv.z + bv.z;
  o.w = (v.w - m) * rstd * gv.w + bv.w;
  yr[t] = o;
}

// ---------------- pack input-side weights to bf16: win=[3][1024][1024] ----
__global__ __launch_bounds__(256) void k_pack_win(const float* __restrict__ wz,
    const float* __restrict__ wr, const float* __restrict__ wh,
    u16* __restrict__ win) {
  int gid = blockIdx.x;           // 0..3071
  int gate = gid >> 10, o = gid & 1023;
  const float* w = (gate == 0) ? wz : ((gate == 1) ? wr : wh);
  const float* row = w + (size_t)o * (2 * HD);
  int t = threadIdx.x;
  float4 a = ((const float4*)row)[t];
  ushort4 ua;
  ua.x = f2bf(a.x); ua.y = f2bf(a.y); ua.z = f2bf(a.z); ua.w = f2bf(a.w);
  *(ushort4*)(win + (size_t)gid * HD + t * 4) = ua;
}

// ---------------- slice recurrent weights: Wrec[g][o][k] = w_g[o, H+k] ----
__global__ __launch_bounds__(256) void k_slice_w(const float* __restrict__ wz,
    const float* __restrict__ wr, const float* __restrict__ wh,
    float* __restrict__ Wrec) {
  int gid = blockIdx.x;
  int gate = gid >> 10, o = gid & 1023;
  const float* w = (gate == 0) ? wz : ((gate == 1) ? wr : wh);
  int t = threadIdx.x;
  float4 v = ((const float4*)(w + (size_t)o * (2 * HD) + HD))[t];
  ((float4*)(Wrec + ((size_t)gate << 20) + ((size_t)o << 10)))[t] = v;
}

// ---------------- bf16 MFMA GEMM: C[16384,3072] = A[16384,1024] * B[3072,1024]^T
__global__ __launch_bounds__(256) void k_gemm(const u16* __restrict__ A,
    const u16* __restrict__ Bw, u16* __restrict__ C) {
  __shared__ u16 As[128 * 32];
  __shared__ u16 Bs[128 * 32];
  int tid = threadIdx.x;
  int bx = blockIdx.x % 24;       // N tile
  int by = blockIdx.x / 24;       // M tile
  int m0 = by * 128, n0 = bx * 128;
  int lane = tid & 63, wave = tid >> 6;
  int wr = wave >> 1, wc = wave & 1;
  int rl = lane & 15, kq = (lane >> 4) * 8;
  f32x4 acc[4][4] = {};
  int srow = tid >> 2, skb = (tid & 3) * 8;
  for (int k0 = 0; k0 < 1024; k0 += 32) {
    __syncthreads();
#pragma unroll
    for (int i = 0; i < 2; i++) {
      int row = srow + i * 64;
      uint4 av = *(const uint4*)(A + (size_t)(m0 + row) * 1024 + k0 + skb);
      *(uint4*)(As + row * 32 + skb) = av;
      uint4 bv = *(const uint4*)(Bw + (size_t)(n0 + row) * 1024 + k0 + skb);
      *(uint4*)(Bs + row * 32 + skb) = bv;
    }
    __syncthreads();
    bf16x8 af[4], bg[4];
#pragma unroll
    for (int mi = 0; mi < 4; mi++)
      af[mi] = *(const bf16x8*)(As + (wr * 64 + mi * 16 + rl) * 32 + kq);
#pragma unroll
    for (int ni = 0; ni < 4; ni++)
      bg[ni] = *(const bf16x8*)(Bs + (wc * 64 + ni * 16 + rl) * 32 + kq);
#pragma unroll
    for (int mi = 0; mi < 4; mi++)
#pragma unroll
      for (int ni = 0; ni < 4; ni++)
        acc[mi][ni] = __builtin_amdgcn_mfma_f32_16x16x32_bf16(af[mi], bg[ni], acc[mi][ni], 0, 0, 0);
  }
  int rowq = (lane >> 4) * 4;
#pragma unroll
  for (int mi = 0; mi < 4; mi++)
#pragma unroll
    for (int ni = 0; ni < 4; ni++)
#pragma unroll
      for (int r = 0; r < 4; r++) {
        int row = m0 + wr * 64 + mi * 16 + rowq + r;
        int col = n0 + wc * 64 + ni * 16 + rl;
        C[(size_t)row * 3072 + col] = f2bf(acc[mi][ni][r]);
      }
}

// ---------------- persistent recurrence kernel, batch-fused ----------------
// 256 blocks x 512 threads; block bid owns outputs [bid*4, bid*4+4) for ALL
// 8 batches (weight-stationary: 48KB weights/block/step, L2-resident).
// Wave w handles batch w end-to-end. Exchange: fp32 [8][1024] vectors,
// staged once per block (8 pipelined cload2/thread) -> LDS, conflict-free
// [jj*64+ln] reads. Global barrier: 8 lines x 32 arrivals + t0 scalar poll.
__global__ __launch_bounds__(NTHR, 1) void k_rec(
    float* __restrict__ hx, float* __restrict__ ux,
    const float* __restrict__ Wrec, const u16* __restrict__ gx,
    const float* __restrict__ bz, const float* __restrict__ br,
    const float* __restrict__ bh, const float* __restrict__ g_st,
    const float* __restrict__ b_st, const float* __restrict__ h0,
    float* __restrict__ out, float* __restrict__ hfin,
    u32* __restrict__ bar) {
  __shared__ float hbuf[BB * HD];   // 32KB
  __shared__ float ubuf[BB * HD];   // 32KB
  const int t = threadIdx.x;
  const int bid = blockIdx.x;
  const int w8 = t >> 6, ln = t & 63;
  const int o0 = bid * 4;

  // weight granules (float4): gate stride 2^18, row stride 256
  const float4* wrow = (const float4*)Wrec + (size_t)o0 * 256;
  const float4 bz4 = *(const float4*)(bz + o0);
  const float4 br4 = *(const float4*)(br + o0);
  const float4 bh4 = *(const float4*)(bh + o0);
  const float4 gmo = ((const float4*)g_st)[bid];
  const float4 bto = ((const float4*)b_st)[bid];
  float4 gm[4], bt[4];
#pragma unroll
  for (int jj = 0; jj < 4; jj++) {
    gm[jj] = ((const float4*)g_st)[jj * 64 + ln];
    bt[jj] = ((const float4*)b_st)[jj * 64 + ln];
  }
  const u16* gbase = gx + ((size_t)w8 * LL) * 3072 + o0;
  float* outp = out + ((size_t)w8 * LL) * HD + o0;
  const u64* hx64 = (const u64*)hx;
  const u64* ux64 = (const u64*)ux;

  float4 hom = *(const float4*)(h0 + w8 * HD + o0);   // fp32 master state
  u64 gz8 = *(const u64*)(gbase);
  u64 gr8 = *(const u64*)(gbase + 1024);
  u64 gh8 = *(const u64*)(gbase + 2048);

  for (int step = 0; step < LL; step++) {
    // ---- stage h[all batches]: 8 pipelined cload2 -> LDS ----
#pragma unroll
    for (int i = 0; i < 8; i++)
      ((float2*)hbuf)[i * 512 + t] = cload2f(hx64 + i * 512 + t);
    __syncthreads();
    // ---- wave-private LN stats for batch w8, hn slices in registers ----
    float4 hn[4];
    float s = 0.f, ss = 0.f;
#pragma unroll
    for (int jj = 0; jj < 4; jj++) {
      float4 v = ((const float4*)hbuf)[w8 * 256 + jj * 64 + ln];
      hn[jj] = v;
      s += (v.x + v.y) + (v.z + v.w);
      ss = fmaf(v.x, v.x, fmaf(v.y, v.y, fmaf(v.z, v.z, fmaf(v.w, v.w, ss))));
    }
#pragma unroll
    for (int mk = 1; mk < 64; mk <<= 1) { s += __shfl_xor(s, mk); ss += __shfl_xor(ss, mk); }
    float m = s * (1.0f / HD);
    float rstd = rsqrtf(ss * (1.0f / HD) - m * m + 1e-5f);
#pragma unroll
    for (int jj = 0; jj < 4; jj++) {
      hn[jj].x = fmaf((hn[jj].x - m) * rstd, gm[jj].x, bt[jj].x);
      hn[jj].y = fmaf((hn[jj].y - m) * rstd, gm[jj].y, bt[jj].y);
      hn[jj].z = fmaf((hn[jj].z - m) * rstd, gm[jj].z, bt[jj].z);
      hn[jj].w = fmaf((hn[jj].w - m) * rstd, gm[jj].w, bt[jj].w);
    }
    float4 hro = ((const float4*)hbuf)[w8 * 256 + bid];   // own outputs' h
    float4 hno;
    hno.x = fmaf((hro.x - m) * rstd, gmo.x, bto.x);
    hno.y = fmaf((hro.y - m) * rstd, gmo.y, bto.y);
    hno.z = fmaf((hro.z - m) * rstd, gmo.z, bto.z);
    hno.w = fmaf((hro.w - m) * rstd, gmo.w, bto.w);
    // ---- r gate dots (fp32 float4 weights, shared across waves via L1) ----
    float a0 = 0.f, a1 = 0.f, a2 = 0.f, a3 = 0.f;
#pragma unroll
    for (int jj = 0; jj < 4; jj++) {
      int idx = (1 << 18) + jj * 64 + ln;
      a0 += dot4(wrow[idx], hn[jj]);
      a1 += dot4(wrow[idx + 256], hn[jj]);
      a2 += dot4(wrow[idx + 512], hn[jj]);
      a3 += dot4(wrow[idx + 768], hn[jj]);
    }
#pragma unroll
    for (int mk = 1; mk < 64; mk <<= 1) {
      a0 += __shfl_xor(a0, mk); a1 += __shfl_xor(a1, mk);
      a2 += __shfl_xor(a2, mk); a3 += __shfl_xor(a3, mk);
    }
    float4 gr4 = unpk4g(gr8);
    float4 u4;
    u4.x = sigmoidf(a0 + gr4.x + br4.x) * hno.x;
    u4.y = sigmoidf(a1 + gr4.y + br4.y) * hno.y;
    u4.z = sigmoidf(a2 + gr4.z + br4.z) * hno.z;
    u4.w = sigmoidf(a3 + gr4.w + br4.w) * hno.w;
    if (ln < 4) {
      float pv = (ln == 0) ? u4.x : ((ln == 1) ? u4.y : ((ln == 2) ? u4.z : u4.w));
      cstore1(ux + w8 * HD + o0 + ln, pv);
    }
    __syncthreads();                    // drains publish (vmcnt 0)
    if (t == 0) bar_arrive(bar, 2 * step, bid);
    // ---- z gate from hn registers, overlapped with barrier-A wait ----
    a0 = 0.f; a1 = 0.f; a2 = 0.f; a3 = 0.f;
#pragma unroll
    for (int jj = 0; jj < 4; jj++) {
      int idx = jj * 64 + ln;
      a0 += dot4(wrow[idx], hn[jj]);
      a1 += dot4(wrow[idx + 256], hn[jj]);
      a2 += dot4(wrow[idx + 512], hn[jj]);
      a3 += dot4(wrow[idx + 768], hn[jj]);
    }
#pragma unroll
    for (int mk = 1; mk < 64; mk <<= 1) {
      a0 += __shfl_xor(a0, mk); a1 += __shfl_xor(a1, mk);
      a2 += __shfl_xor(a2, mk); a3 += __shfl_xor(a3, mk);
    }
    float4 gz4 = unpk4g(gz8);
    float4 zv;
    zv.x = sigmoidf(a0 + gz4.x + bz4.x);
    zv.y = sigmoidf(a1 + gz4.y + bz4.y);
    zv.z = sigmoidf(a2 + gz4.z + bz4.z);
    zv.w = sigmoidf(a3 + gz4.w + bz4.w);
    if (t == 0) bar_wait(bar, 2 * step);
    __syncthreads();
    // ---- stage u[all batches] -> LDS ----
#pragma unroll
    for (int i = 0; i < 8; i++)
      ((float2*)ubuf)[i * 512 + t] = cload2f(ux64 + i * 512 + t);
    __syncthreads();
    // ---- h_cand dots over u of batch w8 ----
    a0 = 0.f; a1 = 0.f; a2 = 0.f; a3 = 0.f;
#pragma unroll
    for (int jj = 0; jj < 4; jj++) {
      float4 uu = ((const float4*)ubuf)[w8 * 256 + jj * 64 + ln];
      int idx = (2 << 18) + jj * 64 + ln;
      a0 += dot4(wrow[idx], uu);
      a1 += dot4(wrow[idx + 256], uu);
      a2 += dot4(wrow[idx + 512], uu);
      a3 += dot4(wrow[idx + 768], uu);
    }
#pragma unroll
    for (int mk = 1; mk < 64; mk <<= 1) {
      a0 += __shfl_xor(a0, mk); a1 += __shfl_xor(a1, mk);
      a2 += __shfl_xor(a2, mk); a3 += __shfl_xor(a3, mk);
    }
    float4 gh4 = unpk4g(gh8);
    float4 hnew;
    hnew.x = fmaf(zv.x, tanhf(a0 + gh4.x + bh4.x) - hom.x, hom.x);
    hnew.y = fmaf(zv.y, tanhf(a1 + gh4.y + bh4.y) - hom.y, hom.y);
    hnew.z = fmaf(zv.z, tanhf(a2 + gh4.z + bh4.z) - hom.z, hom.z);
    hnew.w = fmaf(zv.w, tanhf(a3 + gh4.w + bh4.w) - hom.w, hom.w);
    hom = hnew;
    if (ln < 4) {
      float pv = (ln == 0) ? hnew.x : ((ln == 1) ? hnew.y : ((ln == 2) ? hnew.z : hnew.w));
      cstore1(hx + w8 * HD + o0 + ln, pv);
    }
    __syncthreads();                    // drains publish
    if (t == 0) bar_arrive(bar, 2 * step + 1, bid);
    // ---- overlapped with barrier-B wait: out store + next gx prefetch ----
    if (ln == 0) *(float4*)outp = hnew;
    outp += HD;
    if (step == LL - 1 && ln == 0) *(float4*)(hfin + w8 * HD + o0) = hnew;
    int ns = (step + 1 < LL) ? (step + 1) : step;
    const u16* gn = gbase + (size_t)ns * 3072;
    gz8 = *(const u64*)(gn);
    gr8 = *(const u64*)(gn + 1024);
    gh8 = *(const u64*)(gn + 2048);
    if (t == 0) bar_wait(bar, 2 * step + 1);
    __syncthreads();
  }
}

__global__ __launch_bounds__(256) void k_copy(const float* __restrict__ src,
    float* __restrict__ dst, int n4) {
  int i = blockIdx.x * blockDim.x + threadIdx.x;
  if (i < n4) ((float4*)dst)[i] = ((const float4*)src)[i];
}

extern "C" void kernel_launch(void* const* d_in, const int* in_sizes, int n_in,
                              void* d_out, int out_size, void* d_ws, size_t ws_size,
                              hipStream_t stream) {
  (void)in_sizes; (void)n_in; (void)out_size; (void)ws_size;
  const float* x    = (const float*)d_in[0];
  const float* h0   = (const float*)d_in[1];
  const float* wz   = (const float*)d_in[2];
  const float* bz   = (const float*)d_in[3];
  const float* wr   = (const float*)d_in[4];
  const float* br   = (const float*)d_in[5];
  const float* wh   = (const float*)d_in[6];
  const float* bh   = (const float*)d_in[7];
  const float* g_in = (const float*)d_in[8];
  const float* b_in = (const float*)d_in[9];
  const float* g_st = (const float*)d_in[10];
  const float* b_st = (const float*)d_in[11];
  const float* g_out= (const float*)d_in[12];
  const float* b_out= (const float*)d_in[13];
  float* out = (float*)d_out;

  char* ws = (char*)d_ws;
  // region A [0,32MB): xn during frontend; fp32 recurrent weights after gemm
  u16*   xn   = (u16*)(ws);
  float* Wrec = (float*)(ws);                       // 12 MB (after gemm)
  // region B: input-side bf16 weights
  u16*   win  = (u16*)(ws + 33554432ull);           //  6 MB
  // region C: gx
  u16*   gx   = (u16*)(ws + 39845888ull);           // 96 MB -> ends 140509184
  // region D: exchange buffers + counters + final state
  float* hx   = (float*)(ws + 140509184ull);        // 32 KB fp32 [8][1024]
  float* ux   = (float*)(ws + 140541952ull);        // 32 KB fp32 [8][1024]
  u32*   bar  = (u32*)(ws + 140574720ull);          //  4 KB counters
  float* hfin = (float*)(ws + 140578816ull);        // 32 KB

  k_pack_win<<<dim3(3072), dim3(256), 0, stream>>>(wz, wr, wh, win);
  k_ln_x<<<dim3(16384), dim3(256), 0, stream>>>(x, g_in, b_in, xn);
  k_gemm<<<dim3(3072), dim3(256), 0, stream>>>(xn, win, gx);
  // after gemm: xn region is dead -> write fp32 recurrent weights there
  k_slice_w<<<dim3(3072), dim3(256), 0, stream>>>(wz, wr, wh, Wrec);
  hipMemsetAsync(bar, 0, 4096, stream);
  hipMemcpyAsync(hx, h0, (size_t)BB * HD * sizeof(float),
                 hipMemcpyDeviceToDevice, stream);
  k_rec<<<dim3(NBLK), dim3(NTHR), 0, stream>>>(hx, ux, Wrec, gx, bz, br, bh,
                                               g_st, b_st, h0, out, hfin, bar);
  k_out_ln<<<dim3(16384), dim3(256), 0, stream>>>(out, g_out, b_out);
  k_copy<<<dim3(8), dim3(256), 0, stream>>>(hfin, out + (size_t)16384 * 1024, 2048);
}

// Round 14
// 14455.180 us; speedup vs baseline: 3.2818x; 3.2818x over previous
//
#include <hip/hip_runtime.h>
#include <stdint.h>
#include <math.h>

#define HD 1024
#define BB 8
#define LL 2048
#define NBLK 256
#define NTHR 512

typedef unsigned short u16;
typedef unsigned int u32;
typedef unsigned long long u64;

using bf16x8 = __attribute__((ext_vector_type(8))) short;
using f32x4  = __attribute__((ext_vector_type(4))) float;

__device__ __forceinline__ u16 f2bf(float f) {
  u32 x = __float_as_uint(f);
  x += 0x7fffu + ((x >> 16) & 1u);
  return (u16)(x >> 16);
}
__device__ __forceinline__ float bf2f(u16 u) {
  return __uint_as_float(((u32)u) << 16);
}
__device__ __forceinline__ float dot4(float4 a, float4 b) {
  return fmaf(a.x, b.x, fmaf(a.y, b.y, fmaf(a.z, b.z, a.w * b.w)));
}
__device__ __forceinline__ float sigmoidf(float x) { return 1.f / (1.f + expf(-x)); }
// u64 of 4 consecutive bf16 -> float4
__device__ __forceinline__ float4 unpk4g(u64 v) {
  u32 lo = (u32)v, hi = (u32)(v >> 32);
  float4 f;
  f.x = __uint_as_float(lo << 16);
  f.y = __uint_as_float(lo & 0xffff0000u);
  f.z = __uint_as_float(hi << 16);
  f.w = __uint_as_float(hi & 0xffff0000u);
  return f;
}

// ---- coherent LLC accesses via relaxed agent atomics (compiler-tracked) ----
__device__ __forceinline__ float2 cload2(const u64* p) {
  u64 v = __hip_atomic_load(p, __ATOMIC_RELAXED, __HIP_MEMORY_SCOPE_AGENT);
  float2 r;
  r.x = __uint_as_float((u32)v);
  r.y = __uint_as_float((u32)(v >> 32));
  return r;
}
__device__ __forceinline__ void cstore1(float* p, float a) {
  __hip_atomic_store((u32*)p, __float_as_uint(a), __ATOMIC_RELAXED, __HIP_MEMORY_SCOPE_AGENT);
}

// ---- per-batch barrier: 32 blocks on ONE line; monotonic, 4 cycling insts ----
// line for (batch b, inst) at u32 index (b*4+inst)*16 (64B apart).  [r8-proven]
__device__ __forceinline__ void bar_arrive(u32* bar, int b, int n) {
  int inst = n & 3;
  __hip_atomic_fetch_add(&bar[(b * 4 + inst) * 16], 1u,
                         __ATOMIC_RELAXED, __HIP_MEMORY_SCOPE_AGENT);
}
__device__ __forceinline__ void bar_wait(u32* bar, int b, int n) {
  int inst = n & 3;
  u32 tgt = (u32)((n >> 2) + 1) * 32u;
  while (__hip_atomic_load(&bar[(b * 4 + inst) * 16],
                           __ATOMIC_RELAXED, __HIP_MEMORY_SCOPE_AGENT) < tgt)
    __builtin_amdgcn_s_sleep(1);
}

// ---------------- input LN: x [16384,1024] f32 -> xn bf16 ----------------
__global__ __launch_bounds__(256) void k_ln_x(const float* __restrict__ x,
    const float* __restrict__ g, const float* __restrict__ b,
    u16* __restrict__ xn) {
  int row = blockIdx.x;
  int t = threadIdx.x;
  const float4* xr = (const float4*)(x + (size_t)row * HD);
  float4 v = xr[t];
  float s = v.x + v.y + v.z + v.w;
  float ss = v.x * v.x + v.y * v.y + v.z * v.z + v.w * v.w;
#pragma unroll
  for (int off = 32; off; off >>= 1) { s += __shfl_down(s, off); ss += __shfl_down(ss, off); }
  __shared__ float red[8];
  if ((t & 63) == 0) { red[t >> 6] = s; red[4 + (t >> 6)] = ss; }
  __syncthreads();
  s = red[0] + red[1] + red[2] + red[3];
  ss = red[4] + red[5] + red[6] + red[7];
  float m = s * (1.0f / HD);
  float rstd = rsqrtf(ss * (1.0f / HD) - m * m + 1e-5f);
  float4 gv = ((const float4*)g)[t];
  float4 bv = ((const float4*)b)[t];
  ushort4 o;
  o.x = f2bf((v.x - m) * rstd * gv.x + bv.x);
  o.y = f2bf((v.y - m) * rstd * gv.y + bv.y);
  o.z = f2bf((v.z - m) * rstd * gv.z + bv.z);
  o.w = f2bf((v.w - m) * rstd * gv.w + bv.w);
  *(ushort4*)(xn + (size_t)row * HD + t * 4) = o;
}

// ---------------- output LN, in place on f32 rows ----------------
__global__ __launch_bounds__(256) void k_out_ln(float* __restrict__ y,
    const float* __restrict__ g, const float* __restrict__ b) {
  int row = blockIdx.x;
  int t = threadIdx.x;
  float4* yr = (float4*)(y + (size_t)row * HD);
  float4 v = yr[t];
  float s = v.x + v.y + v.z + v.w;
  float ss = v.x * v.x + v.y * v.y + v.z * v.z + v.w * v.w;
#pragma unroll
  for (int off = 32; off; off >>= 1) { s += __shfl_down(s, off); ss += __shfl_down(ss, off); }
  __shared__ float red[8];
  if ((t & 63) == 0) { red[t >> 6] = s; red[4 + (t >> 6)] = ss; }
  __syncthreads();
  s = red[0] + red[1] + red[2] + red[3];
  ss = red[4] + red[5] + red[6] + red[7];
  float m = s * (1.0f / HD);
  float rstd = rsqrtf(ss * (1.0f / HD) - m * m + 1e-5f);
  float4 gv = ((const float4*)g)[t];
  float4 bv = ((const float4*)b)[t];
  float4 o;
  o.x = (v.x - m) * rstd * gv.x + bv.x;
  o.y = (v.y - m) * rstd * gv.y + bv.y;
  o.z = (v.z - m) * rstd * gv.z + bv.z;
  o.w = (v.w - m) * rstd * gv.w + bv.w;
  yr[t] = o;
}

// ---------------- pack input-side weights to bf16: win=[3][1024][1024] ----
__global__ __launch_bounds__(256) void k_pack_win(const float* __restrict__ wz,
    const float* __restrict__ wr, const float* __restrict__ wh,
    u16* __restrict__ win) {
  int gid = blockIdx.x;           // 0..3071
  int gate = gid >> 10, o = gid & 1023;
  const float* w = (gate == 0) ? wz : ((gate == 1) ? wr : wh);
  const float* row = w + (size_t)o * (2 * HD);
  int t = threadIdx.x;
  float4 a = ((const float4*)row)[t];
  ushort4 ua;
  ua.x = f2bf(a.x); ua.y = f2bf(a.y); ua.z = f2bf(a.z); ua.w = f2bf(a.w);
  *(ushort4*)(win + (size_t)gid * HD + t * 4) = ua;
}

// ---------------- slice recurrent weights: Wrec[g][o][k] = w_g[o, H+k] ----
__global__ __launch_bounds__(256) void k_slice_w(const float* __restrict__ wz,
    const float* __restrict__ wr, const float* __restrict__ wh,
    float* __restrict__ Wrec) {
  int gid = blockIdx.x;
  int gate = gid >> 10, o = gid & 1023;
  const float* w = (gate == 0) ? wz : ((gate == 1) ? wr : wh);
  int t = threadIdx.x;
  float4 v = ((const float4*)(w + (size_t)o * (2 * HD) + HD))[t];
  ((float4*)(Wrec + ((size_t)gate << 20) + ((size_t)o << 10)))[t] = v;
}

// ---------------- bf16 MFMA GEMM: C[16384,3072] = A[16384,1024] * B[3072,1024]^T
__global__ __launch_bounds__(256) void k_gemm(const u16* __restrict__ A,
    const u16* __restrict__ Bw, u16* __restrict__ C) {
  __shared__ u16 As[128 * 32];
  __shared__ u16 Bs[128 * 32];
  int tid = threadIdx.x;
  int bx = blockIdx.x % 24;       // N tile
  int by = blockIdx.x / 24;       // M tile
  int m0 = by * 128, n0 = bx * 128;
  int lane = tid & 63, wave = tid >> 6;
  int wr = wave >> 1, wc = wave & 1;
  int rl = lane & 15, kq = (lane >> 4) * 8;
  f32x4 acc[4][4] = {};
  int srow = tid >> 2, skb = (tid & 3) * 8;
  for (int k0 = 0; k0 < 1024; k0 += 32) {
    __syncthreads();
#pragma unroll
    for (int i = 0; i < 2; i++) {
      int row = srow + i * 64;
      uint4 av = *(const uint4*)(A + (size_t)(m0 + row) * 1024 + k0 + skb);
      *(uint4*)(As + row * 32 + skb) = av;
      uint4 bv = *(const uint4*)(Bw + (size_t)(n0 + row) * 1024 + k0 + skb);
      *(uint4*)(Bs + row * 32 + skb) = bv;
    }
    __syncthreads();
    bf16x8 af[4], bg[4];
#pragma unroll
    for (int mi = 0; mi < 4; mi++)
      af[mi] = *(const bf16x8*)(As + (wr * 64 + mi * 16 + rl) * 32 + kq);
#pragma unroll
    for (int ni = 0; ni < 4; ni++)
      bg[ni] = *(const bf16x8*)(Bs + (wc * 64 + ni * 16 + rl) * 32 + kq);
#pragma unroll
    for (int mi = 0; mi < 4; mi++)
#pragma unroll
      for (int ni = 0; ni < 4; ni++)
        acc[mi][ni] = __builtin_amdgcn_mfma_f32_16x16x32_bf16(af[mi], bg[ni], acc[mi][ni], 0, 0, 0);
  }
  int rowq = (lane >> 4) * 4;
#pragma unroll
  for (int mi = 0; mi < 4; mi++)
#pragma unroll
    for (int ni = 0; ni < 4; ni++)
#pragma unroll
      for (int r = 0; r < 4; r++) {
        int row = m0 + wr * 64 + mi * 16 + rowq + r;
        int col = n0 + wc * 64 + ni * 16 + rl;
        C[(size_t)row * 3072 + col] = f2bf(acc[mi][ni][r]);
      }
}

// ---------------- persistent recurrence kernel, batch-split (r8 + fixes) ---
// 256 blocks = 8 batches x 32 output-blocks (bid = b*32 + ob). Block handles
// outputs [ob*32, ob*32+32) of batch b; wave w8 owns 4 outputs, replicated in
// all 64 lanes. Stage: 1 cload2/thread -> LDS; block LN stats via red2.
// Slice/weight traversal [jj*64+ln]: LDS conflict-free + coalesced weights.
__global__ __launch_bounds__(NTHR, 1) void k_rec(
    float* __restrict__ hglob, float* __restrict__ rglob,
    const float* __restrict__ Wrec, const u16* __restrict__ gx,
    const float* __restrict__ bz, const float* __restrict__ br,
    const float* __restrict__ bh, const float* __restrict__ g_st,
    const float* __restrict__ b_st, const float* __restrict__ h0,
    float* __restrict__ out, u32* __restrict__ bar) {
  __shared__ float hn_s[HD];
  __shared__ float u_s[HD];
  __shared__ float2 red2[8];
  const int t = threadIdx.x;
  const int bid = blockIdx.x;
  const int b = bid >> 5, ob = bid & 31;
  const int w8 = t >> 6, ln = t & 63;
  const int o0 = ob * 32 + w8 * 4;

  // weight base (float4 units): gate stride 2^18, row stride 256
  const float4* w4 = (const float4*)(Wrec + (size_t)o0 * HD);
  const float4 bz4 = *(const float4*)(bz + o0);
  const float4 br4 = *(const float4*)(br + o0);
  const float4 bh4 = *(const float4*)(bh + o0);
  const float2 gm2 = ((const float2*)g_st)[t];
  const float2 bt2 = ((const float2*)b_st)[t];
  const u16* gbase = gx + ((size_t)b * LL) * 3072 + o0;  // +0:z +1024:r +2048:h
  float* outp = out + ((size_t)b * LL) * HD + o0;
  const u64* hsrc = (const u64*)(hglob + (size_t)b * HD) + t;
  const u64* rsrc = (const u64*)(rglob + (size_t)b * HD) + t;
  float* hpub = hglob + b * HD + o0;
  float* rpub = rglob + b * HD + o0;

  float4 hom = *(const float4*)(h0 + b * HD + o0);   // fp32 master, replicated
  u64 gz8 = *(const u64*)(gbase);
  u64 gr8 = *(const u64*)(gbase + 1024);
  u64 gh8 = *(const u64*)(gbase + 2048);

  for (int step = 0; step < LL; step++) {
    // ---- stage h (1 cload2/thread) + block LN stats + hn -> LDS ----
    float2 h2 = cload2(hsrc);
    float s = h2.x + h2.y;
    float ss = fmaf(h2.x, h2.x, h2.y * h2.y);
#pragma unroll
    for (int mk = 1; mk < 64; mk <<= 1) { s += __shfl_xor(s, mk); ss += __shfl_xor(ss, mk); }
    if (ln == 0) { float2 rv; rv.x = s; rv.y = ss; red2[w8] = rv; }
    __syncthreads();
    s = 0.f; ss = 0.f;
#pragma unroll
    for (int i = 0; i < 8; i++) { float2 rv = red2[i]; s += rv.x; ss += rv.y; }
    float m = s * (1.0f / HD);
    float rstd = rsqrtf(ss * (1.0f / HD) - m * m + 1e-5f);
    float2 hn;
    hn.x = fmaf((h2.x - m) * rstd, gm2.x, bt2.x);
    hn.y = fmaf((h2.y - m) * rstd, gm2.y, bt2.y);
    ((float2*)hn_s)[t] = hn;
    __syncthreads();
    // ---- hn slices, conflict-free [jj*64+ln] (16B lane stride) ----
    float4 hsl[4];
#pragma unroll
    for (int jj = 0; jj < 4; jj++) hsl[jj] = ((const float4*)hn_s)[jj * 64 + ln];
    // ---- r gate: 4 outputs per wave, 64-lane dots ----
    float a0 = 0.f, a1 = 0.f, a2 = 0.f, a3 = 0.f;
#pragma unroll
    for (int jj = 0; jj < 4; jj++) {
      int ix = (1 << 18) + jj * 64 + ln;
      float4 h4 = hsl[jj];
      a0 += dot4(w4[ix], h4);
      a1 += dot4(w4[ix + 256], h4);
      a2 += dot4(w4[ix + 512], h4);
      a3 += dot4(w4[ix + 768], h4);
    }
#pragma unroll
    for (int mk = 1; mk < 64; mk <<= 1) {
      a0 += __shfl_xor(a0, mk); a1 += __shfl_xor(a1, mk);
      a2 += __shfl_xor(a2, mk); a3 += __shfl_xor(a3, mk);
    }
    float4 gr4 = unpk4g(gr8);
    float4 rv4;
    rv4.x = sigmoidf(a0 + gr4.x + br4.x);
    rv4.y = sigmoidf(a1 + gr4.y + br4.y);
    rv4.z = sigmoidf(a2 + gr4.z + br4.z);
    rv4.w = sigmoidf(a3 + gr4.w + br4.w);
    if (ln < 4) {
      float pv = (ln == 0) ? rv4.x : ((ln == 1) ? rv4.y : ((ln == 2) ? rv4.z : rv4.w));
      cstore1(rpub + ln, pv);
    }
    __syncthreads();                  // drains sc1 store before arrive
    if (t == 0) bar_arrive(bar, b, 2 * step);
    // ---- z gate from hsl registers, overlapped with barrier-A wait ----
    a0 = 0.f; a1 = 0.f; a2 = 0.f; a3 = 0.f;
#pragma unroll
    for (int jj = 0; jj < 4; jj++) {
      int ix = jj * 64 + ln;
      float4 h4 = hsl[jj];
      a0 += dot4(w4[ix], h4);
      a1 += dot4(w4[ix + 256], h4);
      a2 += dot4(w4[ix + 512], h4);
      a3 += dot4(w4[ix + 768], h4);
    }
#pragma unroll
    for (int mk = 1; mk < 64; mk <<= 1) {
      a0 += __shfl_xor(a0, mk); a1 += __shfl_xor(a1, mk);
      a2 += __shfl_xor(a2, mk); a3 += __shfl_xor(a3, mk);
    }
    float4 gz4 = unpk4g(gz8);
    float4 zv;
    zv.x = sigmoidf(a0 + gz4.x + bz4.x);
    zv.y = sigmoidf(a1 + gz4.y + bz4.y);
    zv.z = sigmoidf(a2 + gz4.z + bz4.z);
    zv.w = sigmoidf(a3 + gz4.w + bz4.w);
    if (t == 0) bar_wait(bar, b, 2 * step);
    __syncthreads();
    // ---- stage r, compute u = r*hn -> LDS ----
    float2 rr = cload2(rsrc);
    float2 uu;
    uu.x = rr.x * hn.x;
    uu.y = rr.y * hn.y;
    ((float2*)u_s)[t] = uu;
    __syncthreads();
    // ---- phase 2: single dot Wh . u ----
    a0 = 0.f; a1 = 0.f; a2 = 0.f; a3 = 0.f;
#pragma unroll
    for (int jj = 0; jj < 4; jj++) {
      int ix = (2 << 18) + jj * 64 + ln;
      float4 u4 = ((const float4*)u_s)[jj * 64 + ln];
      a0 += dot4(w4[ix], u4);
      a1 += dot4(w4[ix + 256], u4);
      a2 += dot4(w4[ix + 512], u4);
      a3 += dot4(w4[ix + 768], u4);
    }
#pragma unroll
    for (int mk = 1; mk < 64; mk <<= 1) {
      a0 += __shfl_xor(a0, mk); a1 += __shfl_xor(a1, mk);
      a2 += __shfl_xor(a2, mk); a3 += __shfl_xor(a3, mk);
    }
    float4 gh4 = unpk4g(gh8);
    float4 hnew;
    hnew.x = fmaf(zv.x, tanhf(a0 + gh4.x + bh4.x) - hom.x, hom.x);
    hnew.y = fmaf(zv.y, tanhf(a1 + gh4.y + bh4.y) - hom.y, hom.y);
    hnew.z = fmaf(zv.z, tanhf(a2 + gh4.z + bh4.z) - hom.z, hom.z);
    hnew.w = fmaf(zv.w, tanhf(a3 + gh4.w + bh4.w) - hom.w, hom.w);
    hom = hnew;
    if (ln < 4) {
      float pv = (ln == 0) ? hnew.x : ((ln == 1) ? hnew.y : ((ln == 2) ? hnew.z : hnew.w));
      cstore1(hpub + ln, pv);
    }
    __syncthreads();                  // drains sc1 store before arrive
    if (t == 0) bar_arrive(bar, b, 2 * step + 1);
    // ---- overlapped with barrier-B wait: out store + next gx prefetch ----
    if (ln == 0) *(float4*)outp = hnew;
    outp += HD;
    int ns = (step + 1 < LL) ? (step + 1) : step;
    const u16* gn = gbase + (size_t)ns * 3072;
    gz8 = *(const u64*)(gn);
    gr8 = *(const u64*)(gn + 1024);
    gh8 = *(const u64*)(gn + 2048);
    if (t == 0) bar_wait(bar, b, 2 * step + 1);
    __syncthreads();
  }
}

__global__ __launch_bounds__(256) void k_copy(const float* __restrict__ src,
    float* __restrict__ dst, int n4) {
  int i = blockIdx.x * blockDim.x + threadIdx.x;
  if (i < n4) ((float4*)dst)[i] = ((const float4*)src)[i];
}

extern "C" void kernel_launch(void* const* d_in, const int* in_sizes, int n_in,
                              void* d_out, int out_size, void* d_ws, size_t ws_size,
                              hipStream_t stream) {
  (void)in_sizes; (void)n_in; (void)out_size; (void)ws_size;
  const float* x    = (const float*)d_in[0];
  const float* h0   = (const float*)d_in[1];
  const float* wz   = (const float*)d_in[2];
  const float* bz   = (const float*)d_in[3];
  const float* wr   = (const float*)d_in[4];
  const float* br   = (const float*)d_in[5];
  const float* wh   = (const float*)d_in[6];
  const float* bh   = (const float*)d_in[7];
  const float* g_in = (const float*)d_in[8];
  const float* b_in = (const float*)d_in[9];
  const float* g_st = (const float*)d_in[10];
  const float* b_st = (const float*)d_in[11];
  const float* g_out= (const float*)d_in[12];
  const float* b_out= (const float*)d_in[13];
  float* out = (float*)d_out;

  char* ws = (char*)d_ws;
  // region A [0,32MB): xn during frontend; fp32 recurrent weights after gemm
  u16*   xn   = (u16*)(ws);
  float* Wrec = (float*)(ws);                       // 12 MB (after gemm)
  // region B: input-side bf16 weights
  u16*   win  = (u16*)(ws + 33554432ull);           //  6 MB
  // region C: gx
  u16*   gx   = (u16*)(ws + 39845888ull);           // 96 MB -> ends 140509184
  // region D: persistent small buffers
  float* hgl  = (float*)(ws + 140509184ull);        // 32 KB fp32 state
  float* rgl  = (float*)(ws + 140541952ull);        // 32 KB fp32 r broadcast
  u32*   bar  = (u32*)(ws + 140574720ull);          //  4 KB barrier counters

  k_pack_win<<<dim3(3072), dim3(256), 0, stream>>>(wz, wr, wh, win);
  k_ln_x<<<dim3(16384), dim3(256), 0, stream>>>(x, g_in, b_in, xn);
  k_gemm<<<dim3(3072), dim3(256), 0, stream>>>(xn, win, gx);
  // after gemm: xn region is dead -> write fp32 recurrent weights there
  k_slice_w<<<dim3(3072), dim3(256), 0, stream>>>(wz, wr, wh, Wrec);
  hipMemsetAsync(bar, 0, 4096, stream);
  hipMemcpyAsync(hgl, h0, (size_t)BB * HD * sizeof(float),
                 hipMemcpyDeviceToDevice, stream);
  k_rec<<<dim3(NBLK), dim3(NTHR), 0, stream>>>(hgl, rgl, Wrec, gx, bz, br, bh,
                                               g_st, b_st, h0, out, bar);
  k_out_ln<<<dim3(16384), dim3(256), 0, stream>>>(out, g_out, b_out);
  k_copy<<<dim3(8), dim3(256), 0, stream>>>(hgl, out + (size_t)16384 * 1024, 2048);
}

// Round 15
// 10911.044 us; speedup vs baseline: 4.3478x; 1.3248x over previous
//
#include <hip/hip_runtime.h>
#include <stdint.h>
#include <math.h>

#define HD 1024
#define BB 8
#define LL 2048
#define NBLK 256
#define NTHR 512

typedef unsigned short u16;
typedef unsigned int u32;
typedef unsigned long long u64;

using bf16x8 = __attribute__((ext_vector_type(8))) short;
using f32x4  = __attribute__((ext_vector_type(4))) float;

__device__ __forceinline__ u16 f2bf(float f) {
  u32 x = __float_as_uint(f);
  x += 0x7fffu + ((x >> 16) & 1u);
  return (u16)(x >> 16);
}
__device__ __forceinline__ float bf2f(u16 u) {
  return __uint_as_float(((u32)u) << 16);
}
__device__ __forceinline__ float dot4(float4 a, float4 b) {
  return fmaf(a.x, b.x, fmaf(a.y, b.y, fmaf(a.z, b.z, a.w * b.w)));
}
__device__ __forceinline__ float sigmoidf(float x) { return 1.f / (1.f + expf(-x)); }

// ---- coherent LLC accesses via relaxed agent atomics (compiler-tracked) ----
__device__ __forceinline__ float2 cload2(const u64* p) {
  u64 v = __hip_atomic_load(p, __ATOMIC_RELAXED, __HIP_MEMORY_SCOPE_AGENT);
  float2 r;
  r.x = __uint_as_float((u32)v);
  r.y = __uint_as_float((u32)(v >> 32));
  return r;
}
__device__ __forceinline__ void cstore1(float* p, float a) {
  __hip_atomic_store((u32*)p, __float_as_uint(a), __ATOMIC_RELAXED, __HIP_MEMORY_SCOPE_AGENT);
}

// ---- per-batch barrier: 32 blocks on ONE line; monotonic, 4 cycling insts ----
// line for (batch b, inst) at u32 index (b*4+inst)*16 (64B apart).  [r8-proven]
__device__ __forceinline__ void bar_arrive(u32* bar, int b, int n) {
  int inst = n & 3;
  __hip_atomic_fetch_add(&bar[(b * 4 + inst) * 16], 1u,
                         __ATOMIC_RELAXED, __HIP_MEMORY_SCOPE_AGENT);
}
__device__ __forceinline__ void bar_wait(u32* bar, int b, int n) {
  int inst = n & 3;
  u32 tgt = (u32)((n >> 2) + 1) * 32u;
  while (__hip_atomic_load(&bar[(b * 4 + inst) * 16],
                           __ATOMIC_RELAXED, __HIP_MEMORY_SCOPE_AGENT) < tgt)
    __builtin_amdgcn_s_sleep(1);
}

// ---------------- input LN: x [16384,1024] f32 -> xn bf16 ----------------
__global__ __launch_bounds__(256) void k_ln_x(const float* __restrict__ x,
    const float* __restrict__ g, const float* __restrict__ b,
    u16* __restrict__ xn) {
  int row = blockIdx.x;
  int t = threadIdx.x;
  const float4* xr = (const float4*)(x + (size_t)row * HD);
  float4 v = xr[t];
  float s = v.x + v.y + v.z + v.w;
  float ss = v.x * v.x + v.y * v.y + v.z * v.z + v.w * v.w;
#pragma unroll
  for (int off = 32; off; off >>= 1) { s += __shfl_down(s, off); ss += __shfl_down(ss, off); }
  __shared__ float red[8];
  if ((t & 63) == 0) { red[t >> 6] = s; red[4 + (t >> 6)] = ss; }
  __syncthreads();
  s = red[0] + red[1] + red[2] + red[3];
  ss = red[4] + red[5] + red[6] + red[7];
  float m = s * (1.0f / HD);
  float rstd = rsqrtf(ss * (1.0f / HD) - m * m + 1e-5f);
  float4 gv = ((const float4*)g)[t];
  float4 bv = ((const float4*)b)[t];
  ushort4 o;
  o.x = f2bf((v.x - m) * rstd * gv.x + bv.x);
  o.y = f2bf((v.y - m) * rstd * gv.y + bv.y);
  o.z = f2bf((v.z - m) * rstd * gv.z + bv.z);
  o.w = f2bf((v.w - m) * rstd * gv.w + bv.w);
  *(ushort4*)(xn + (size_t)row * HD + t * 4) = o;
}

// ---------------- output LN, in place on f32 rows ----------------
__global__ __launch_bounds__(256) void k_out_ln(float* __restrict__ y,
    const float* __restrict__ g, const float* __restrict__ b) {
  int row = blockIdx.x;
  int t = threadIdx.x;
  float4* yr = (float4*)(y + (size_t)row * HD);
  float4 v = yr[t];
  float s = v.x + v.y + v.z + v.w;
  float ss = v.x * v.x + v.y * v.y + v.z * v.z + v.w * v.w;
#pragma unroll
  for (int off = 32; off; off >>= 1) { s += __shfl_down(s, off); ss += __shfl_down(ss, off); }
  __shared__ float red[8];
  if ((t & 63) == 0) { red[t >> 6] = s; red[4 + (t >> 6)] = ss; }
  __syncthreads();
  s = red[0] + red[1] + red[2] + red[3];
  ss = red[4] + red[5] + red[6] + red[7];
  float m = s * (1.0f / HD);
  float rstd = rsqrtf(ss * (1.0f / HD) - m * m + 1e-5f);
  float4 gv = ((const float4*)g)[t];
  float4 bv = ((const float4*)b)[t];
  float4 o;
  o.x = (v.x - m) * rstd * gv.x + bv.x;
  o.y = (v.y - m) * rstd * gv.y + bv.y;
  o.z = (v.z - m) * rstd * gv.z + bv.z;
  o.w = (v.w - m) * rstd * gv.w + bv.w;
  yr[t] = o;
}

// ---------------- pack input-side weights to bf16: win=[3][1024][1024] ----
__global__ __launch_bounds__(256) void k_pack_win(const float* __restrict__ wz,
    const float* __restrict__ wr, const float* __restrict__ wh,
    u16* __restrict__ win) {
  int gid = blockIdx.x;           // 0..3071
  int gate = gid >> 10, o = gid & 1023;
  const float* w = (gate == 0) ? wz : ((gate == 1) ? wr : wh);
  const float* row = w + (size_t)o * (2 * HD);
  int t = threadIdx.x;
  float4 a = ((const float4*)row)[t];
  ushort4 ua;
  ua.x = f2bf(a.x); ua.y = f2bf(a.y); ua.z = f2bf(a.z); ua.w = f2bf(a.w);
  *(ushort4*)(win + (size_t)gid * HD + t * 4) = ua;
}

// ---------------- slice recurrent weights: Wrec[g][o][k] = w_g[o, H+k] ----
__global__ __launch_bounds__(256) void k_slice_w(const float* __restrict__ wz,
    const float* __restrict__ wr, const float* __restrict__ wh,
    float* __restrict__ Wrec) {
  int gid = blockIdx.x;
  int gate = gid >> 10, o = gid & 1023;
  const float* w = (gate == 0) ? wz : ((gate == 1) ? wr : wh);
  int t = threadIdx.x;
  float4 v = ((const float4*)(w + (size_t)o * (2 * HD) + HD))[t];
  ((float4*)(Wrec + ((size_t)gate << 20) + ((size_t)o << 10)))[t] = v;
}

// ---------------- bf16 MFMA GEMM: C[16384,3072] = A[16384,1024] * B[3072,1024]^T
__global__ __launch_bounds__(256) void k_gemm(const u16* __restrict__ A,
    const u16* __restrict__ Bw, u16* __restrict__ C) {
  __shared__ u16 As[128 * 32];
  __shared__ u16 Bs[128 * 32];
  int tid = threadIdx.x;
  int bx = blockIdx.x % 24;       // N tile
  int by = blockIdx.x / 24;       // M tile
  int m0 = by * 128, n0 = bx * 128;
  int lane = tid & 63, wave = tid >> 6;
  int wr = wave >> 1, wc = wave & 1;
  int rl = lane & 15, kq = (lane >> 4) * 8;
  f32x4 acc[4][4] = {};
  int srow = tid >> 2, skb = (tid & 3) * 8;
  for (int k0 = 0; k0 < 1024; k0 += 32) {
    __syncthreads();
#pragma unroll
    for (int i = 0; i < 2; i++) {
      int row = srow + i * 64;
      uint4 av = *(const uint4*)(A + (size_t)(m0 + row) * 1024 + k0 + skb);
      *(uint4*)(As + row * 32 + skb) = av;
      uint4 bv = *(const uint4*)(Bw + (size_t)(n0 + row) * 1024 + k0 + skb);
      *(uint4*)(Bs + row * 32 + skb) = bv;
    }
    __syncthreads();
    bf16x8 af[4], bg[4];
#pragma unroll
    for (int mi = 0; mi < 4; mi++)
      af[mi] = *(const bf16x8*)(As + (wr * 64 + mi * 16 + rl) * 32 + kq);
#pragma unroll
    for (int ni = 0; ni < 4; ni++)
      bg[ni] = *(const bf16x8*)(Bs + (wc * 64 + ni * 16 + rl) * 32 + kq);
#pragma unroll
    for (int mi = 0; mi < 4; mi++)
#pragma unroll
      for (int ni = 0; ni < 4; ni++)
        acc[mi][ni] = __builtin_amdgcn_mfma_f32_16x16x32_bf16(af[mi], bg[ni], acc[mi][ni], 0, 0, 0);
  }
  int rowq = (lane >> 4) * 4;
#pragma unroll
  for (int mi = 0; mi < 4; mi++)
#pragma unroll
    for (int ni = 0; ni < 4; ni++)
#pragma unroll
      for (int r = 0; r < 4; r++) {
        int row = m0 + wr * 64 + mi * 16 + rowq + r;
        int col = n0 + wc * 64 + ni * 16 + rl;
        C[(size_t)row * 3072 + col] = f2bf(acc[mi][ni][r]);
      }
}

// ---------------- persistent recurrence kernel, batch-split ----------------
// 256 blocks = 8 batches x 32 output-blocks (bid = b*32 + ob). Block handles
// outputs [ob*32, ob*32+32) of batch b. Wave w8 owns outputs o0..o0+3; the
// epilogue is LANE-PARALLEL (lane q<4 computes output o0+q's transcendentals).
// Memory traversal [jj*64+ln]: LDS conflict-free (16B lane stride) and weight
// loads 1KB-contiguous per instruction.  All sync/transport idioms = r8.
__global__ __launch_bounds__(NTHR, 1) void k_rec(
    float* __restrict__ hglob, float* __restrict__ rglob,
    const float* __restrict__ Wrec, const u16* __restrict__ gx,
    const float* __restrict__ bz, const float* __restrict__ br,
    const float* __restrict__ bh, const float* __restrict__ g_st,
    const float* __restrict__ b_st, const float* __restrict__ h0,
    float* __restrict__ out, u32* __restrict__ bar) {
  __shared__ float hn_s[HD];
  __shared__ float u_s[HD];
  __shared__ float2 red2[8];
  const int t = threadIdx.x;
  const int bid = blockIdx.x;
  const int b = bid >> 5, ob = bid & 31;
  const int w8 = t >> 6, ln = t & 63;
  const int q = ln & 3;
  const int o0 = ob * 32 + w8 * 4;
  const int o_fin = o0 + q;                 // output handled by lanes ln<4

  // weight base (float4 units): gate stride 2^18, row stride 256
  const float4* w4 = (const float4*)(Wrec + (size_t)o0 * HD);
  const float biZ = bz[o_fin], biR = br[o_fin], bhc = bh[o_fin];
  const float2 gm2 = ((const float2*)g_st)[t];
  const float2 bt2 = ((const float2*)b_st)[t];
  const u16* gp = gx + ((size_t)b * LL) * 3072 + o_fin;  // +0:z +1024:r +2048:h
  float* outp = out + ((size_t)b * LL) * HD + o_fin;
  const u64* hsrc = (const u64*)(hglob + (size_t)b * HD) + t;
  const u64* rsrc = (const u64*)(rglob + (size_t)b * HD) + t;
  float* hpub = hglob + b * HD + o_fin;
  float* rpub = rglob + b * HD + o_fin;

  float ho = h0[b * HD + o_fin];                 // master state (lanes ln<4)
  u16 gZ = gp[0], gR = gp[1024], gH = gp[2048];  // step-0 gx prefetch
  gp += 3072;

  for (int step = 0; step < LL; step++) {
    // ---- stage h (1 cload2/thread) + block LN stats + hn -> LDS ----
    float2 h2 = cload2(hsrc);
    float s = h2.x + h2.y;
    float ss = fmaf(h2.x, h2.x, h2.y * h2.y);
#pragma unroll
    for (int mk = 1; mk < 64; mk <<= 1) { s += __shfl_xor(s, mk); ss += __shfl_xor(ss, mk); }
    if (ln == 0) { float2 rv; rv.x = s; rv.y = ss; red2[w8] = rv; }
    __syncthreads();
    s = 0.f; ss = 0.f;
#pragma unroll
    for (int i = 0; i < 8; i++) { float2 rv = red2[i]; s += rv.x; ss += rv.y; }
    float m = s * (1.0f / HD);
    float rstd = rsqrtf(ss * (1.0f / HD) - m * m + 1e-5f);
    float2 hn;
    hn.x = fmaf((h2.x - m) * rstd, gm2.x, bt2.x);
    hn.y = fmaf((h2.y - m) * rstd, gm2.y, bt2.y);
    ((float2*)hn_s)[t] = hn;
    __syncthreads();
    // ---- hn slices, conflict-free [jj*64+ln] (16B lane stride) ----
    float4 hsl[4];
#pragma unroll
    for (int jj = 0; jj < 4; jj++) hsl[jj] = ((const float4*)hn_s)[jj * 64 + ln];
    // ---- r gate: 4 outputs per wave, 64-lane dots ----
    float a0 = 0.f, a1 = 0.f, a2 = 0.f, a3 = 0.f;
#pragma unroll
    for (int jj = 0; jj < 4; jj++) {
      int ix = (1 << 18) + jj * 64 + ln;
      float4 h4 = hsl[jj];
      a0 += dot4(w4[ix], h4);
      a1 += dot4(w4[ix + 256], h4);
      a2 += dot4(w4[ix + 512], h4);
      a3 += dot4(w4[ix + 768], h4);
    }
#pragma unroll
    for (int mk = 1; mk < 64; mk <<= 1) {
      a0 += __shfl_xor(a0, mk); a1 += __shfl_xor(a1, mk);
      a2 += __shfl_xor(a2, mk); a3 += __shfl_xor(a3, mk);
    }
    if (ln < 4) {
      float av = (q == 0) ? a0 : ((q == 1) ? a1 : ((q == 2) ? a2 : a3));
      cstore1(rpub, sigmoidf(av + bf2f(gR) + biR));
    }
    __syncthreads();                  // drains sc1 store before arrive
    if (t == 0) bar_arrive(bar, b, 2 * step);
    // ---- z gate from the same hn slices, overlapped with barrier-A wait ----
    a0 = 0.f; a1 = 0.f; a2 = 0.f; a3 = 0.f;
#pragma unroll
    for (int jj = 0; jj < 4; jj++) {
      int ix = jj * 64 + ln;
      float4 h4 = hsl[jj];
      a0 += dot4(w4[ix], h4);
      a1 += dot4(w4[ix + 256], h4);
      a2 += dot4(w4[ix + 512], h4);
      a3 += dot4(w4[ix + 768], h4);
    }
#pragma unroll
    for (int mk = 1; mk < 64; mk <<= 1) {
      a0 += __shfl_xor(a0, mk); a1 += __shfl_xor(a1, mk);
      a2 += __shfl_xor(a2, mk); a3 += __shfl_xor(a3, mk);
    }
    float zv = 0.f;
    if (ln < 4) {
      float av = (q == 0) ? a0 : ((q == 1) ? a1 : ((q == 2) ? a2 : a3));
      zv = sigmoidf(av + bf2f(gZ) + biZ);
    }
    if (t == 0) bar_wait(bar, b, 2 * step);
    __syncthreads();
    // ---- stage r, compute u = r*hn -> LDS ----
    float2 rr = cload2(rsrc);
    float2 uu;
    uu.x = rr.x * hn.x;
    uu.y = rr.y * hn.y;
    ((float2*)u_s)[t] = uu;
    __syncthreads();
    // ---- phase 2: single dot Wh . u ----
    a0 = 0.f; a1 = 0.f; a2 = 0.f; a3 = 0.f;
#pragma unroll
    for (int jj = 0; jj < 4; jj++) {
      int ix = (2 << 18) + jj * 64 + ln;
      float4 u4 = ((const float4*)u_s)[jj * 64 + ln];
      a0 += dot4(w4[ix], u4);
      a1 += dot4(w4[ix + 256], u4);
      a2 += dot4(w4[ix + 512], u4);
      a3 += dot4(w4[ix + 768], u4);
    }
#pragma unroll
    for (int mk = 1; mk < 64; mk <<= 1) {
      a0 += __shfl_xor(a0, mk); a1 += __shfl_xor(a1, mk);
      a2 += __shfl_xor(a2, mk); a3 += __shfl_xor(a3, mk);
    }
    float hnew = 0.f;
    if (ln < 4) {
      float av = (q == 0) ? a0 : ((q == 1) ? a1 : ((q == 2) ? a2 : a3));
      float hc = tanhf(av + bf2f(gH) + bhc);
      hnew = fmaf(zv, hc - ho, ho);
      ho = hnew;
      cstore1(hpub, hnew);
    }
    __syncthreads();                  // drains sc1 store before arrive
    if (t == 0) bar_arrive(bar, b, 2 * step + 1);
    // ---- overlapped with barrier-B wait: out store + next gx prefetch ----
    if (ln < 4) outp[0] = hnew;
    outp += HD;
    gZ = gp[0]; gR = gp[1024]; gH = gp[2048];
    gp += 3072;
    if (t == 0) bar_wait(bar, b, 2 * step + 1);
    __syncthreads();
  }
}

__global__ __launch_bounds__(256) void k_copy(const float* __restrict__ src,
    float* __restrict__ dst, int n4) {
  int i = blockIdx.x * blockDim.x + threadIdx.x;
  if (i < n4) ((float4*)dst)[i] = ((const float4*)src)[i];
}

extern "C" void kernel_launch(void* const* d_in, const int* in_sizes, int n_in,
                              void* d_out, int out_size, void* d_ws, size_t ws_size,
                              hipStream_t stream) {
  (void)in_sizes; (void)n_in; (void)out_size; (void)ws_size;
  const float* x    = (const float*)d_in[0];
  const float* h0   = (const float*)d_in[1];
  const float* wz   = (const float*)d_in[2];
  const float* bz   = (const float*)d_in[3];
  const float* wr   = (const float*)d_in[4];
  const float* br   = (const float*)d_in[5];
  const float* wh   = (const float*)d_in[6];
  const float* bh   = (const float*)d_in[7];
  const float* g_in = (const float*)d_in[8];
  const float* b_in = (const float*)d_in[9];
  const float* g_st = (const float*)d_in[10];
  const float* b_st = (const float*)d_in[11];
  const float* g_out= (const float*)d_in[12];
  const float* b_out= (const float*)d_in[13];
  float* out = (float*)d_out;

  char* ws = (char*)d_ws;
  // region A [0,32MB): xn during frontend; fp32 recurrent weights after gemm
  u16*   xn   = (u16*)(ws);
  float* Wrec = (float*)(ws);                       // 12 MB (after gemm)
  // region B: input-side bf16 weights
  u16*   win  = (u16*)(ws + 33554432ull);           //  6 MB
  // region C: gx
  u16*   gx   = (u16*)(ws + 39845888ull);           // 96 MB -> ends 140509184
  // region D: persistent small buffers
  float* hgl  = (float*)(ws + 140509184ull);        // 32 KB fp32 state
  float* rgl  = (float*)(ws + 140541952ull);        // 32 KB fp32 r broadcast
  u32*   bar  = (u32*)(ws + 140574720ull);          //  4 KB barrier counters

  k_pack_win<<<dim3(3072), dim3(256), 0, stream>>>(wz, wr, wh, win);
  k_ln_x<<<dim3(16384), dim3(256), 0, stream>>>(x, g_in, b_in, xn);
  k_gemm<<<dim3(3072), dim3(256), 0, stream>>>(xn, win, gx);
  // after gemm: xn region is dead -> write fp32 recurrent weights there
  k_slice_w<<<dim3(3072), dim3(256), 0, stream>>>(wz, wr, wh, Wrec);
  hipMemsetAsync(bar, 0, 4096, stream);
  hipMemcpyAsync(hgl, h0, (size_t)BB * HD * sizeof(float),
                 hipMemcpyDeviceToDevice, stream);
  k_rec<<<dim3(NBLK), dim3(NTHR), 0, stream>>>(hgl, rgl, Wrec, gx, bz, br, bh,
                                               g_st, b_st, h0, out, bar);
  k_out_ln<<<dim3(16384), dim3(256), 0, stream>>>(out, g_out, b_out);
  k_copy<<<dim3(8), dim3(256), 0, stream>>>(hgl, out + (size_t)16384 * 1024, 2048);
}